// Round 4
// baseline (5998.275 us; speedup 1.0000x reference)
//
#include <hip/hip_runtime.h>
#include <stdint.h>
#include <math.h>

// ---------------------------------------------------------------------------
// GausskeyL2P: ViT-B/16 x2 passes + MVN gaussian-key prompt selection.
// Round 7: right-looking blocked Cholesky (NB=64) replaces the 10-CU
// panel monolith:
//   chol_diag : 64x64 diag factor, 1 wave/pool (grid 10), full shfl unroll
//   trsm_off  : L21 = A21 L11^-T, one THREAD per row (R*10 threads), L11 LDS
//   syrk_upd  : A22 -= L21 L21^T rank-64, grid (R/64)^2 x 10 (up to 1210 blk)
// Same FLOPs, same ascending-k order per element (partial-sum application
// order differs -> fp32-negligible drift). GEMMs unchanged from R6.
// ---------------------------------------------------------------------------

typedef _Float16 h16_t;
typedef _Float16 h8v __attribute__((ext_vector_type(8)));
typedef _Float16 h4v __attribute__((ext_vector_type(4)));
typedef float    f4v __attribute__((ext_vector_type(4)));

#define DEV static __device__ __forceinline__

DEV float wred64(float s) {
#pragma unroll
  for (int m = 1; m < 64; m <<= 1) s += __shfl_xor(s, m, 64);
  return s;
}
DEV float gelu_f(float x) {  // jax.nn.gelu approximate=True (tanh form)
  float u = 0.7978845608028654f * x * (1.0f + 0.044715f * x * x);
  u = fminf(fmaxf(u, -30.0f), 30.0f);
  float e = __expf(-2.0f * u);
  return 0.5f * x * (1.0f + (1.0f - e) / (1.0f + e));
}

#define GLD16(gp, lp) __builtin_amdgcn_global_load_lds( \
  (const __attribute__((address_space(1))) unsigned int*)(const void*)(gp), \
  (__attribute__((address_space(3))) unsigned int*)(void*)(lp), 16, 0, 0)

// ---------------------------------------------------------------------------
// Staging: R x (512 thr x 16 B) = R x 8 KiB of [rows][32 k] fp16 half-K
// panels. LDS dest linear; global source pre-swizzled with involution
// P ^= ((P>>7)&3)<<4 so the swizzled ds_reads recover the data.
// ---------------------------------------------------------------------------
template <int R>
DEV void stgN(const h16_t* __restrict__ src, int row0, int rowmax, int ldk,
              char* ldsb, unsigned lbase, int tid) {
#pragma unroll
  for (int r = 0; r < R; r++) {
    unsigned P = ((unsigned)r << 13) + ((unsigned)tid << 4);
    unsigned Q = P ^ (((P >> 7) & 3u) << 4);
    int row = (int)(Q >> 6);
    int kb = (int)((Q & 63u) >> 1);
    int gr = row0 + row; gr = gr < rowmax ? gr : rowmax - 1;
    GLD16(src + (size_t)gr * ldk + kb,
          ldsb + lbase + (r << 13) + ((tid >> 6) << 10));
  }
}

#define FENCE() asm volatile("" ::: "memory")
#define RBAR() do { FENCE(); __builtin_amdgcn_s_barrier(); FENCE(); } while (0)
#define VMW(N) asm volatile("s_waitcnt vmcnt(" #N ")" ::: "memory")

// swizzled LDS frag read of row `row` (64B rows), k-quad `quad`, at region rb
DEV h8v frag_rd(const char* ldsb, unsigned rb, int row, int quad) {
  unsigned P = ((unsigned)row << 6) + ((unsigned)quad << 4);
  P ^= ((P >> 7) & 3u) << 4;
  return *(const h8v*)(ldsb + rb + P);
}

// ---------------------------------------------------------------------------
// hgemm_q: 128x256, BK=64, C16 = A*B^T + bias. N%256==0, K%64==0, K>=192.
// 512 thr, 8 waves 2Mx4N (wave 64x64). LDS 144 KiB = 3 x 48 KiB buffers.
// ---------------------------------------------------------------------------
__global__ __launch_bounds__(512, 2) void hgemm_q(
    const h16_t* __restrict__ A, const h16_t* __restrict__ B,
    h16_t* __restrict__ C16, const float* __restrict__ bias,
    int M, int N, int K, int ldc16)
{
  __shared__ __align__(16) char ldsb[147456];
  int tid = threadIdx.x;
  int w = tid >> 6, lane = tid & 63;
  int wm = w >> 2, wn = w & 3;
  int fr = lane & 15, quad = lane >> 4;
  int m0 = blockIdx.x << 7, n0 = blockIdx.y << 8;

  f4v acc[4][4];
#pragma unroll
  for (int i2 = 0; i2 < 4; i2++)
#pragma unroll
    for (int j2 = 0; j2 < 4; j2++)
#pragma unroll
      for (int r2 = 0; r2 < 4; r2++) acc[i2][j2][r2] = 0.0f;

  int NT = K >> 6;

  auto stage = [&](int t, unsigned bb) {
    stgN<1>(A + (t << 6),      m0, M, K, ldsb, bb,           tid);
    stgN<1>(A + (t << 6) + 32, m0, M, K, ldsb, bb + 8192u,   tid);
    stgN<2>(B + (t << 6),      n0, N, K, ldsb, bb + 16384u,  tid);
    stgN<2>(B + (t << 6) + 32, n0, N, K, ldsb, bb + 32768u,  tid);
  };
  stage(0, 0u);
  stage(1, 49152u);
  VMW(6);
  __builtin_amdgcn_s_barrier();
  FENCE();

  unsigned cb = 0u, sb = 98304u;
  for (int i = 0; i < NT; i++) {
    int tS = (i + 2 < NT) ? i + 2 : NT - 1;
    stage(tS, sb);
    h8v af[2][4], bf[2][4];
#pragma unroll
    for (int kh = 0; kh < 2; kh++)
#pragma unroll
      for (int t = 0; t < 4; t++) {
        af[kh][t] = frag_rd(ldsb, cb + ((unsigned)kh << 13),
                            (wm << 6) + (t << 4) + fr, quad);
        bf[kh][t] = frag_rd(ldsb, cb + 16384u + ((unsigned)kh << 14),
                            (wn << 6) + (t << 4) + fr, quad);
      }
    __builtin_amdgcn_s_setprio(1);
#pragma unroll
    for (int kh = 0; kh < 2; kh++)
#pragma unroll
      for (int ti = 0; ti < 4; ti++)
#pragma unroll
        for (int tj = 0; tj < 4; tj++)
          acc[ti][tj] = __builtin_amdgcn_mfma_f32_16x16x32_f16(af[kh][ti], bf[kh][tj], acc[ti][tj], 0, 0, 0);
    __builtin_amdgcn_s_setprio(0);
    VMW(6);
    RBAR();
    cb = (cb == 98304u) ? 0u : cb + 49152u;
    sb = (sb == 98304u) ? 0u : sb + 49152u;
  }
  asm volatile("s_waitcnt vmcnt(0)" ::: "memory");

  int row0 = m0 + (wm << 6) + (quad << 2);
  int col0 = n0 + (wn << 6) + fr;
  float bv[4];
#pragma unroll
  for (int nj = 0; nj < 4; nj++) bv[nj] = bias[col0 + (nj << 4)];
#pragma unroll
  for (int mi = 0; mi < 4; mi++) {
#pragma unroll
    for (int rg = 0; rg < 4; rg++) {
      int row = row0 + (mi << 4) + rg;
      if (row < M) {
#pragma unroll
        for (int nj = 0; nj < 4; nj++) {
          float v = acc[mi][nj][rg] + bv[nj];
          C16[(size_t)row * ldc16 + col0 + (nj << 4)] = (h16_t)v;
        }
      }
    }
  }
}

// ---------------------------------------------------------------------------
// hgemm_f: 256x256, BK=32, C16 = gelu(A*B^T + bias). N%256==0, K%32==0.
// 512 thr, 8 waves 2Mx4N (wave 128x64). LDS 96 KiB = 3 x 32 KiB.
// ---------------------------------------------------------------------------
__global__ __launch_bounds__(512, 2) void hgemm_f(
    const h16_t* __restrict__ A, const h16_t* __restrict__ B,
    h16_t* __restrict__ C16, const float* __restrict__ bias,
    int M, int N, int K, int ldc16)
{
  __shared__ __align__(16) char ldsb[98304];
  int tid = threadIdx.x;
  int w = tid >> 6, lane = tid & 63;
  int wm = w >> 2, wn = w & 3;
  int fr = lane & 15, quad = lane >> 4;
  int m0 = blockIdx.x << 8, n0 = blockIdx.y << 8;

  f4v acc[8][4];
#pragma unroll
  for (int i2 = 0; i2 < 8; i2++)
#pragma unroll
    for (int j2 = 0; j2 < 4; j2++)
#pragma unroll
      for (int r2 = 0; r2 < 4; r2++) acc[i2][j2][r2] = 0.0f;

  int NT = K >> 5;

  auto stage = [&](int t, unsigned bb) {
    stgN<2>(A + (t << 5), m0, M, K, ldsb, bb,          tid);
    stgN<2>(B + (t << 5), n0, N, K, ldsb, bb + 16384u, tid);
  };
  stage(0, 0u);
  stage(1, 32768u);
  VMW(4);
  __builtin_amdgcn_s_barrier();
  FENCE();

  unsigned cb = 0u, sb = 65536u;
  for (int i = 0; i < NT; i++) {
    int tS = (i + 2 < NT) ? i + 2 : NT - 1;
    stage(tS, sb);
    h8v af[8], bf[4];
#pragma unroll
    for (int t = 0; t < 8; t++)
      af[t] = frag_rd(ldsb, cb, (wm << 7) + (t << 4) + fr, quad);
#pragma unroll
    for (int t = 0; t < 4; t++)
      bf[t] = frag_rd(ldsb, cb + 16384u, (wn << 6) + (t << 4) + fr, quad);
    __builtin_amdgcn_s_setprio(1);
#pragma unroll
    for (int ti = 0; ti < 8; ti++)
#pragma unroll
      for (int tj = 0; tj < 4; tj++)
        acc[ti][tj] = __builtin_amdgcn_mfma_f32_16x16x32_f16(af[ti], bf[tj], acc[ti][tj], 0, 0, 0);
    __builtin_amdgcn_s_setprio(0);
    VMW(4);
    RBAR();
    cb = (cb == 65536u) ? 0u : cb + 32768u;
    sb = (sb == 65536u) ? 0u : sb + 32768u;
  }
  asm volatile("s_waitcnt vmcnt(0)" ::: "memory");

  int row0 = m0 + (wm << 7) + (quad << 2);
  int col0 = n0 + (wn << 6) + fr;
  float bv[4];
#pragma unroll
  for (int nj = 0; nj < 4; nj++) bv[nj] = bias[col0 + (nj << 4)];
#pragma unroll
  for (int mi = 0; mi < 8; mi++) {
#pragma unroll
    for (int rg = 0; rg < 4; rg++) {
      int row = row0 + (mi << 4) + rg;
      if (row < M) {
#pragma unroll
        for (int nj = 0; nj < 4; nj++) {
          float v = gelu_f(acc[mi][nj][rg] + bv[nj]);
          C16[(size_t)row * ldc16 + col0 + (nj << 4)] = (h16_t)v;
        }
      }
    }
  }
}

// ---------------------------------------------------------------------------
// hgemm_p: 128x128, BK=64, C32 = A*B^T + bias [+C32]. N%128==0, K%64==0.
// 512 thr, 8 waves 2Mx4N (wave 64x32). LDS 96 KiB = 3 x 32 KiB.
// ---------------------------------------------------------------------------
__global__ __launch_bounds__(512, 2) void hgemm_p(
    const h16_t* __restrict__ A, const h16_t* __restrict__ B,
    float* __restrict__ C32, const float* __restrict__ bias,
    int M, int N, int K, int ldc, int addC)
{
  __shared__ __align__(16) char ldsb[98304];
  int tid = threadIdx.x;
  int w = tid >> 6, lane = tid & 63;
  int wm = w >> 2, wn = w & 3;
  int fr = lane & 15, quad = lane >> 4;
  int m0 = blockIdx.x << 7, n0 = blockIdx.y << 7;

  f4v acc[4][2];
#pragma unroll
  for (int i2 = 0; i2 < 4; i2++)
#pragma unroll
    for (int j2 = 0; j2 < 2; j2++)
#pragma unroll
      for (int r2 = 0; r2 < 4; r2++) acc[i2][j2][r2] = 0.0f;

  int NT = K >> 6;

  auto stage = [&](int t, unsigned bb) {
    stgN<1>(A + (t << 6),      m0, M, K, ldsb, bb,           tid);
    stgN<1>(A + (t << 6) + 32, m0, M, K, ldsb, bb + 8192u,   tid);
    stgN<1>(B + (t << 6),      n0, N, K, ldsb, bb + 16384u,  tid);
    stgN<1>(B + (t << 6) + 32, n0, N, K, ldsb, bb + 24576u,  tid);
  };
  stage(0, 0u);
  stage(1, 32768u);
  VMW(4);
  __builtin_amdgcn_s_barrier();
  FENCE();

  unsigned cb = 0u, sb = 65536u;
  for (int i = 0; i < NT; i++) {
    int tS = (i + 2 < NT) ? i + 2 : NT - 1;
    stage(tS, sb);
    h8v af[2][4], bf[2][2];
#pragma unroll
    for (int kh = 0; kh < 2; kh++) {
#pragma unroll
      for (int t = 0; t < 4; t++)
        af[kh][t] = frag_rd(ldsb, cb + ((unsigned)kh << 13),
                            (wm << 6) + (t << 4) + fr, quad);
#pragma unroll
      for (int t = 0; t < 2; t++)
        bf[kh][t] = frag_rd(ldsb, cb + 16384u + ((unsigned)kh << 13),
                            (wn << 5) + (t << 4) + fr, quad);
    }
    __builtin_amdgcn_s_setprio(1);
#pragma unroll
    for (int kh = 0; kh < 2; kh++)
#pragma unroll
      for (int ti = 0; ti < 4; ti++)
#pragma unroll
        for (int tj = 0; tj < 2; tj++)
          acc[ti][tj] = __builtin_amdgcn_mfma_f32_16x16x32_f16(af[kh][ti], bf[kh][tj], acc[ti][tj], 0, 0, 0);
    __builtin_amdgcn_s_setprio(0);
    VMW(4);
    RBAR();
    cb = (cb == 65536u) ? 0u : cb + 32768u;
    sb = (sb == 65536u) ? 0u : sb + 32768u;
  }
  asm volatile("s_waitcnt vmcnt(0)" ::: "memory");

  int row0 = m0 + (wm << 6) + (quad << 2);
  int col0 = n0 + (wn << 5) + fr;
  float bv[2];
#pragma unroll
  for (int nj = 0; nj < 2; nj++) bv[nj] = bias[col0 + (nj << 4)];
#pragma unroll
  for (int mi = 0; mi < 4; mi++) {
#pragma unroll
    for (int rg = 0; rg < 4; rg++) {
      int row = row0 + (mi << 4) + rg;
      if (row < M) {
#pragma unroll
        for (int nj = 0; nj < 2; nj++) {
          size_t off = (size_t)row * ldc + col0 + (nj << 4);
          float v = acc[mi][nj][rg] + bv[nj];
          if (addC) v += C32[off];
          C32[off] = v;
        }
      }
    }
  }
}

// ---------------------------------------------------------------------------
// Fused flash attention: qkv16 [B*N, 2304] fp16 (bias applied) -> o [B*N,768]
// grid (ceil(N/64), B*12), 256 thr.
// ---------------------------------------------------------------------------
__global__ __launch_bounds__(256) void flash_attn(
    const h16_t* __restrict__ qkv, h16_t* __restrict__ o, int N)
{
  int z = blockIdx.y;
  int b = z / 12, h = z - (z / 12) * 12;
  const h16_t* base = qkv + (size_t)b * N * 2304 + h * 64;
  int q0 = blockIdx.x << 6;
  int tid = threadIdx.x, w = tid >> 6, lane = tid & 63;
  int fr = lane & 15, fk = (lane >> 4) << 3;
  int quad = lane >> 4;

  __shared__ __align__(16) h16_t Qs[2][64 * 32];
  __shared__ __align__(16) h16_t Ks[2][64 * 32];
  __shared__ __align__(16) h16_t Ps[4][1024];
  __shared__ __align__(16) h16_t Vt[64 * 68];

#pragma unroll
  for (int s = 0; s < 2; s++) {
    int gq = q0 + (w << 4) + (lane >> 2); gq = gq < N ? gq : N - 1;
    GLD16(base + (size_t)gq * 2304 + (s << 5) + ((lane & 3) << 3), &Qs[s][(w << 4) << 5]);
  }
  __syncthreads();
  h8v af0 = *(const h8v*)&Qs[0][(((w << 4) + fr) << 5) + fk];
  h8v af1 = *(const h8v*)&Qs[1][(((w << 4) + fr) << 5) + fk];

  float mrow[4], lrow[4];
  f4v accO[4];
#pragma unroll
  for (int r = 0; r < 4; r++) { mrow[r] = -1e30f; lrow[r] = 0.0f; }
#pragma unroll
  for (int t = 0; t < 4; t++)
#pragma unroll
    for (int r = 0; r < 4; r++) accO[t][r] = 0.0f;

  int nj = (N + 63) >> 6;
  for (int jt = 0; jt < nj; jt++) {
    int j0 = jt << 6;
    __syncthreads();
#pragma unroll
    for (int s = 0; s < 2; s++) {
      int gj = j0 + (w << 4) + (lane >> 2); gj = gj < N ? gj : N - 1;
      GLD16(base + (size_t)gj * 2304 + 768 + (s << 5) + ((lane & 3) << 3), &Ks[s][(w << 4) << 5]);
    }
#pragma unroll
    for (int i = 0; i < 16; i++) {
      int j = (w << 4) + i;
      int gj = j0 + j; gj = gj < N ? gj : N - 1;
      Vt[lane * 68 + j] = base[(size_t)gj * 2304 + 1536 + lane];
    }
    __syncthreads();

    f4v s4[4];
#pragma unroll
    for (int t = 0; t < 4; t++) {
      h8v b0 = *(const h8v*)&Ks[0][(((t << 4) + fr) << 5) + fk];
      h8v b1 = *(const h8v*)&Ks[1][(((t << 4) + fr) << 5) + fk];
      f4v s; s[0] = s[1] = s[2] = s[3] = 0.0f;
      s = __builtin_amdgcn_mfma_f32_16x16x32_f16(af0, b0, s, 0, 0, 0);
      s = __builtin_amdgcn_mfma_f32_16x16x32_f16(af1, b1, s, 0, 0, 0);
      s4[t] = s;
    }
#pragma unroll
    for (int r = 0; r < 4; r++) {
      float tm = -1e30f;
#pragma unroll
      for (int t = 0; t < 4; t++) {
        float v = s4[t][r] * 0.125f;
        if (j0 + (t << 4) + fr >= N) v = -1e30f;
        s4[t][r] = v;
        tm = fmaxf(tm, v);
      }
#pragma unroll
      for (int m = 1; m < 16; m <<= 1) tm = fmaxf(tm, __shfl_xor(tm, m, 64));
      float mn = fmaxf(mrow[r], tm);
      float alpha = __expf(mrow[r] - mn);
      mrow[r] = mn;
      float rs = 0.0f;
#pragma unroll
      for (int t = 0; t < 4; t++) {
        float e = __expf(s4[t][r] - mn);
        s4[t][r] = e;
        rs += e;
      }
#pragma unroll
      for (int m = 1; m < 16; m <<= 1) rs += __shfl_xor(rs, m, 64);
      lrow[r] = lrow[r] * alpha + rs;
#pragma unroll
      for (int t = 0; t < 4; t++) accO[t][r] *= alpha;
#pragma unroll
      for (int t = 0; t < 4; t++)
        Ps[w][((t >> 1) << 9) + (((quad << 2) + r) << 5) + ((t & 1) << 4) + fr] = (h16_t)s4[t][r];
    }
#pragma unroll
    for (int s = 0; s < 2; s++) {
      h8v ap = *(const h8v*)&Ps[w][(s << 9) + (fr << 5) + fk];
#pragma unroll
      for (int t = 0; t < 4; t++) {
        int vidx = ((t << 4) + fr) * 68 + (s << 5) + fk;
        h4v v0 = *(const h4v*)&Vt[vidx];
        h4v v1 = *(const h4v*)&Vt[vidx + 4];
        h8v bv;
#pragma unroll
        for (int i = 0; i < 4; i++) { bv[i] = v0[i]; bv[i + 4] = v1[i]; }
        accO[t] = __builtin_amdgcn_mfma_f32_16x16x32_f16(ap, bv, accO[t], 0, 0, 0);
      }
    }
  }

#pragma unroll
  for (int r = 0; r < 4; r++) {
    int q = q0 + (w << 4) + (quad << 2) + r;
    if (q >= N) continue;
    float inv = 1.0f / lrow[r];
    h16_t* op = o + ((size_t)b * N + q) * 768 + h * 64 + fr;
#pragma unroll
    for (int t = 0; t < 4; t++) op[t << 4] = (h16_t)(accO[t][r] * inv);
  }
}

// ---------------- weight convert: fp32 [K,N] -> fp16 [N,K] (batched z) ------
__global__ __launch_bounds__(256) void wcvt_t(const float* __restrict__ in,
                                              h16_t* __restrict__ o, int K, int N) {
  int z = blockIdx.z;
  in += (size_t)z * K * N;
  o  += (size_t)z * K * N;
  int n0 = blockIdx.x << 5, k0 = blockIdx.y << 5;
  __shared__ float t[32][33];
  int a = threadIdx.x >> 3, b4 = (threadIdx.x & 7) << 2;
  f4v v = *(const f4v*)(in + (size_t)(k0 + a) * N + n0 + b4);
  t[a][b4] = v[0]; t[a][b4 + 1] = v[1]; t[a][b4 + 2] = v[2]; t[a][b4 + 3] = v[3];
  __syncthreads();
  h4v h;
#pragma unroll
  for (int i = 0; i < 4; i++) h[i] = (h16_t)t[b4 + i][a];
  *(h4v*)(o + (size_t)(n0 + a) * K + k0 + b4) = h;
}

__global__ void cvt_flat(const float* __restrict__ in, h16_t* __restrict__ o, int n) {
  int i = blockIdx.x * 256 + threadIdx.x;
  if (i < n) o[i] = (h16_t)in[i];
}

// ---------------- patch embed im2col (fp16 out) -----------------------------
__global__ void im2col_k(const float* __restrict__ in, h16_t* __restrict__ col) {
  int idx = blockIdx.x * 256 + threadIdx.x;
  if (idx >= 16 * 196 * 768) return;
  int k = idx % 768; int t = idx / 768; int p2 = t % 196; int b = t / 196;
  int c = k >> 8, ij = k & 255, i = ij >> 4, j = ij & 15;
  int py = p2 / 14, px = p2 % 14;
  col[idx] = (h16_t)in[(((size_t)b * 3 + c) * 224 + py * 16 + i) * 224 + px * 16 + j];
}

__global__ void build_x0_k(float* __restrict__ x, const float* __restrict__ img,
                           const float* __restrict__ cls, const float* __restrict__ pos) {
  int idx = blockIdx.x * 256 + threadIdx.x;
  if (idx >= 16 * 197 * 768) return;
  int d = idx % 768; int t = idx / 768; int n = t % 197; int b = t / 197;
  float v = (n == 0) ? cls[d] : img[((size_t)b * 196 + (n - 1)) * 768 + d];
  x[idx] = v + pos[n * 768 + d];
}

__global__ void build_x2_k(float* __restrict__ x, const float* __restrict__ img,
                           const float* __restrict__ cls, const float* __restrict__ pos,
                           const float* __restrict__ prompt, const int* __restrict__ tk) {
  int idx = blockIdx.x * 256 + threadIdx.x;
  if (idx >= 16 * 222 * 768) return;
  int d = idx % 768; int t = idx / 768; int n = t % 222; int b = t / 222;
  float v;
  if (n == 0) v = cls[d] + pos[d];
  else if (n < 26) {
    int s = (n - 1) / 5, li = (n - 1) % 5;
    v = prompt[((size_t)tk[b * 5 + s] * 5 + li) * 768 + d] + pos[d];
  } else {
    v = img[((size_t)b * 196 + (n - 26)) * 768 + d];
  }
  x[idx] = v;
}

// ---------------- LayerNorm rows (wave per row), fp16 and/or fp32 out -------
__global__ void ln_rows(const float* __restrict__ in, h16_t* __restrict__ o16,
                        float* __restrict__ o32, const float* __restrict__ g,
                        const float* __restrict__ b, int rows, long istr, long ostr) {
  int gw = ((blockIdx.x << 8) + threadIdx.x) >> 6;
  int lane = threadIdx.x & 63;
  if (gw >= rows) return;
  const float* rp = in + (size_t)gw * istr;
  float v[12]; float s = 0;
#pragma unroll
  for (int i = 0; i < 12; i++) { v[i] = rp[lane + (i << 6)]; s += v[i]; }
  s = wred64(s);
  float mean = s * (1.0f / 768.0f);
  float s2 = 0;
#pragma unroll
  for (int i = 0; i < 12; i++) { float d = v[i] - mean; s2 += d * d; }
  s2 = wred64(s2);
  float rstd = rsqrtf(s2 * (1.0f / 768.0f) + 1e-6f);
#pragma unroll
  for (int i = 0; i < 12; i++) {
    int k = lane + (i << 6);
    float o = (v[i] - mean) * rstd * g[k] + b[k];
    if (o16) o16[(size_t)gw * ostr + k] = (h16_t)o;
    if (o32) o32[(size_t)gw * ostr + k] = o;
  }
}

// ---------------- Cholesky (right-looking, NB=64) ---------------------------
__global__ void cov_init_k(const float* __restrict__ var, float* __restrict__ Lb) {
  size_t i = (size_t)blockIdx.x * 256 + threadIdx.x;
  if (i >= (size_t)10 * 589824) return;
  int ij = (int)(i % 589824);
  int r = ij / 768, c = ij - r * 768;
  Lb[i] = fabsf(var[i]) + ((r == c) ? 1.0f : 0.0f);
}

// factor the 64x64 diag block at (jb,jb): one wave per pool. Lane r = row r.
// Rows r only update cols c <= r, so upper-triangle junk is never touched and
// never feeds a broadcast (shfl sources are lanes j and c > j, both proper).
__global__ __launch_bounds__(64) void chol_diag(float* __restrict__ Lb, int jb) {
  int p = blockIdx.x;
  float* base = Lb + (size_t)p * 589824 + (size_t)jb * 768 + jb;
  int r = threadIdx.x;
  float* rp = base + (size_t)r * 768;
  float a[64];
#pragma unroll
  for (int i = 0; i < 16; i++) {
    f4v v = *(const f4v*)(rp + 4 * i);
    a[4 * i] = v[0]; a[4 * i + 1] = v[1]; a[4 * i + 2] = v[2]; a[4 * i + 3] = v[3];
  }
#pragma unroll
  for (int j = 0; j < 64; j++) {
    float dv = __shfl(a[j], j, 64);
    float ds = sqrtf(dv);
    float di = 1.0f / ds;
    if (r == j) a[j] = ds;
    else if (r > j) a[j] *= di;
    float lrj = a[j];
#pragma unroll
    for (int c = j + 1; c < 64; c++) {
      float lcj = __shfl(a[j], c, 64);
      if (r >= c) a[c] -= lrj * lcj;
    }
  }
#pragma unroll
  for (int i = 0; i < 16; i++) {
    f4v v;
    v[0] = a[4 * i]; v[1] = a[4 * i + 1]; v[2] = a[4 * i + 2]; v[3] = a[4 * i + 3];
    *(f4v*)(rp + 4 * i) = v;
  }
}

// L21 = A21 * L11^-T: one thread per row (R rows below the diag block).
// L11 (64x64) broadcast from LDS; x[64] fully unrolled (registers).
__global__ __launch_bounds__(256) void trsm_off(float* __restrict__ Lb, int jb, int R) {
  int p = blockIdx.y;
  float* base = Lb + (size_t)p * 589824;
  __shared__ float L11[64][64];
  int tid = threadIdx.x;
  {
    int rr = tid >> 2, cc = (tid & 3) << 4;
    const float* sp = base + (size_t)(jb + rr) * 768 + jb + cc;
#pragma unroll
    for (int i = 0; i < 4; i++)
      *(f4v*)&L11[rr][cc + 4 * i] = *(const f4v*)(sp + 4 * i);
  }
  __syncthreads();
  int r = blockIdx.x * 256 + tid;
  if (r >= R) return;
  float* rp = base + (size_t)(jb + 64 + r) * 768 + jb;
  float x[64];
#pragma unroll
  for (int i = 0; i < 16; i++) {
    f4v v = *(const f4v*)(rp + 4 * i);
    x[4 * i] = v[0]; x[4 * i + 1] = v[1]; x[4 * i + 2] = v[2]; x[4 * i + 3] = v[3];
  }
#pragma unroll
  for (int c = 0; c < 64; c++) {
    float s = x[c];
#pragma unroll
    for (int k = 0; k < c; k++) s -= x[k] * L11[c][k];
    x[c] = s * (1.0f / L11[c][c]);
  }
#pragma unroll
  for (int i = 0; i < 16; i++) {
    f4v v;
    v[0] = x[4 * i]; v[1] = x[4 * i + 1]; v[2] = x[4 * i + 2]; v[3] = x[4 * i + 3];
    *(f4v*)(rp + 4 * i) = v;
  }
}

// A22 -= L21 * L21^T (rank-64). Block (bi,bj) with bj<=bi updates the 64x64
// tile at rows jb+64+64bi, cols jb+64+64bj. K=64 (the just-solved panel).
__global__ __launch_bounds__(256) void syrk_upd(float* __restrict__ Lb, int jb) {
  int bi = blockIdx.x, bj = blockIdx.y;
  if (bj > bi) return;
  int p = blockIdx.z;
  float* base = Lb + (size_t)p * 589824;
  int i0 = jb + 64 + (bi << 6), j0 = jb + 64 + (bj << 6);
  const float* A = base + (size_t)i0 * 768 + jb;
  const float* Bp = base + (size_t)j0 * 768 + jb;
  float* C = base + (size_t)i0 * 768 + j0;
  __shared__ float As[16][64];
  __shared__ float Bs[16][64];
  int tid = threadIdx.x;
  int am = tid & 63, ak = (tid >> 6) << 2;
  int tm = (tid >> 4) << 2, tn = (tid & 15) << 2;
  float acc[4][4] = {};
  for (int k0 = 0; k0 < 64; k0 += 16) {
    f4v va = *(const f4v*)(A + (size_t)am * 768 + k0 + ak);
    f4v vb = *(const f4v*)(Bp + (size_t)am * 768 + k0 + ak);
#pragma unroll
    for (int i = 0; i < 4; i++) { As[ak + i][am] = va[i]; Bs[ak + i][am] = vb[i]; }
    __syncthreads();
#pragma unroll
    for (int kk = 0; kk < 16; kk++) {
      f4v a = *(const f4v*)&As[kk][tm];
      f4v b = *(const f4v*)&Bs[kk][tn];
#pragma unroll
      for (int i = 0; i < 4; i++)
#pragma unroll
        for (int j = 0; j < 4; j++) acc[i][j] += a[i] * b[j];
    }
    __syncthreads();
  }
#pragma unroll
  for (int i = 0; i < 4; i++)
#pragma unroll
    for (int j = 0; j < 4; j++)
      C[(size_t)(tm + i) * 768 + tn + j] -= acc[i][j];
}

// ---------------- L -> Ut (Ut[k][j] = L[j][k] if j>k else 0) + diag ---------
__global__ __launch_bounds__(256) void ltrans_k(const float* __restrict__ Lb,
                                                float* __restrict__ Ut,
                                                float* __restrict__ dg) {
  int p = blockIdx.z;
  const float* L = Lb + (size_t)p * 589824;
  float* U = Ut + (size_t)p * 589824;
  int r0 = blockIdx.x << 5, c0 = blockIdx.y << 5;
  __shared__ float t[32][33];
  int a = threadIdx.x >> 3, b4 = (threadIdx.x & 7) << 2;
  f4v v = *(const f4v*)(L + (size_t)(r0 + a) * 768 + c0 + b4);
  t[a][b4] = v[0]; t[a][b4 + 1] = v[1]; t[a][b4 + 2] = v[2]; t[a][b4 + 3] = v[3];
  __syncthreads();
  int k = c0 + a;
  f4v ov;
#pragma unroll
  for (int i = 0; i < 4; i++) {
    int j = r0 + b4 + i;
    float val = t[b4 + i][a];
    ov[i] = (j > k) ? val : 0.0f;
    if (j == k) dg[p * 768 + k] = val;
  }
  *(f4v*)(U + (size_t)k * 768 + r0 + b4) = ov;
}

// ---------------- column-sweep trsm + logp: 1 wave per (b,p) ----------------
__global__ __launch_bounds__(64) void trsm2(const float* __restrict__ Ut,
                                            const float* __restrict__ dg,
                                            const float* __restrict__ q,
                                            const float* __restrict__ mean,
                                            float* __restrict__ logp) {
  int gw = blockIdx.x;
  int p = gw >> 4, b = gw & 15;
  const float* U = Ut + (size_t)p * 589824;
  int lane = threadIdx.x;

  float y[12], dinv[12];
  float lacc = 0.0f;
#pragma unroll
  for (int m = 0; m < 12; m++) {
    int i = lane + (m << 6);
    y[m] = q[b * 768 + i] - mean[p * 768 + i];
    float d = dg[p * 768 + i];
    dinv[m] = 1.0f / d;
    lacc += __logf(d);
  }

  float u[8][12];
#pragma unroll
  for (int d0 = 0; d0 < 8; d0++)
#pragma unroll
    for (int mm = 0; mm < 12; mm++)
      u[d0][mm] = U[(size_t)d0 * 768 + lane + (mm << 6)];

#pragma unroll
  for (int m = 0; m < 12; m++) {
    for (int kb = 0; kb < 64; kb += 8) {
#pragma unroll
      for (int kd = 0; kd < 8; kd++) {
        int k = (m << 6) + kb + kd;
        float yo = __shfl(y[m], kb + kd, 64);
        float di = __shfl(dinv[m], kb + kd, 64);
        float yk = yo * di;
        if (lane == kb + kd) y[m] = yk;
        // prefetch row k+8 (overwrites slot kd after its use below)
        float un[12];
        bool pf = (k + 8) < 768;
        const float* rp = U + (size_t)(k + 8) * 768 + lane;
#pragma unroll
        for (int mm = 0; mm < 12; mm++) un[mm] = pf ? rp[mm << 6] : 0.0f;
#pragma unroll
        for (int mm = 0; mm < 12; mm++) y[mm] -= u[kd][mm] * yk;
#pragma unroll
        for (int mm = 0; mm < 12; mm++) u[kd][mm] = un[mm];
      }
    }
  }

  float quad = 0.0f;
#pragma unroll
  for (int m = 0; m < 12; m++) quad += y[m] * y[m];
  quad = wred64(quad);
  lacc = wred64(lacc);
  if (lane == 0)
    logp[b * 10 + p] = -0.5f * (768.0f * 1.8378770664093453f + 2.0f * lacc + quad);
}

__global__ void topk_k(const float* __restrict__ logp, int* __restrict__ tk) {
  int b = threadIdx.x;
  if (b >= 16) return;
  float v[10];
#pragma unroll
  for (int p = 0; p < 10; p++) v[p] = logp[b * 10 + p];
#pragma unroll
  for (int s = 0; s < 5; s++) {
    int bi = 0; float bv = v[0];
#pragma unroll
    for (int p = 1; p < 10; p++) if (v[p] > bv) { bv = v[p]; bi = p; }
    tk[b * 5 + s] = bi;
    v[bi] = -3.0e38f;
  }
}

DEV float blocksum256(float s, float* red) {
  s = wred64(s);
  __syncthreads();
  if ((threadIdx.x & 63) == 0) red[threadIdx.x >> 6] = s;
  __syncthreads();
  return red[0] + red[1] + red[2] + red[3];
}

__global__ __launch_bounds__(256) void final_head(const float* __restrict__ x,
                                                  const float* __restrict__ g,
                                                  const float* __restrict__ b,
                                                  const float* __restrict__ hw,
                                                  const float* __restrict__ hb,
                                                  float* __restrict__ out) {
  int bb = blockIdx.x, tid = threadIdx.x;
  __shared__ float xm[768];
  __shared__ float red[4];
  float a0 = 0, a1 = 0, a2 = 0;
  for (int j = 1; j <= 25; j++) {
    const float* rp = x + ((size_t)bb * 222 + j) * 768;
    float v0 = rp[tid], v1 = rp[tid + 256], v2 = rp[tid + 512];
    float s = blocksum256(v0 + v1 + v2, red);
    float mean = s * (1.0f / 768.0f);
    float d0 = v0 - mean, d1 = v1 - mean, d2 = v2 - mean;
    float s2 = blocksum256(d0 * d0 + d1 * d1 + d2 * d2, red);
    float rstd = rsqrtf(s2 * (1.0f / 768.0f) + 1e-6f);
    a0 += d0 * rstd * g[tid] + b[tid];
    a1 += d1 * rstd * g[tid + 256] + b[tid + 256];
    a2 += d2 * rstd * g[tid + 512] + b[tid + 512];
  }
  xm[tid] = a0 * (1.0f / 25.0f);
  xm[tid + 256] = a1 * (1.0f / 25.0f);
  xm[tid + 512] = a2 * (1.0f / 25.0f);
  __syncthreads();
  if (tid < 100) {
    float s = hb[tid];
    for (int d = 0; d < 768; d++) s += xm[d] * hw[d * 100 + tid];
    out[bb * 100 + tid] = s;
  }
}

// ---------------------------------------------------------------------------
extern "C" void kernel_launch(void* const* d_in, const int* in_sizes, int n_in,
                              void* d_out, int out_size, void* d_ws, size_t ws_size,
                              hipStream_t stream) {
  (void)in_sizes; (void)n_in; (void)out_size; (void)ws_size;
  const float* inp     = (const float*)d_in[0];
  const float* patchw  = (const float*)d_in[1];
  const float* patchb  = (const float*)d_in[2];
  const float* cls     = (const float*)d_in[3];
  const float* pos     = (const float*)d_in[4];
  const float* ln1g    = (const float*)d_in[5];
  const float* ln1b    = (const float*)d_in[6];
  const float* qkvw    = (const float*)d_in[7];
  const float* qkvb    = (const float*)d_in[8];
  const float* projw   = (const float*)d_in[9];
  const float* projb   = (const float*)d_in[10];
  const float* ln2g    = (const float*)d_in[11];
  const float* ln2b    = (const float*)d_in[12];
  const float* fc1w    = (const float*)d_in[13];
  const float* fc1b    = (const float*)d_in[14];
  const float* fc2w    = (const float*)d_in[15];
  const float* fc2b    = (const float*)d_in[16];
  const float* normg   = (const float*)d_in[17];
  const float* normb   = (const float*)d_in[18];
  const float* headw   = (const float*)d_in[19];
  const float* headb   = (const float*)d_in[20];
  const float* prompt  = (const float*)d_in[21];
  const float* meanp   = (const float*)d_in[22];
  const float* var     = (const float*)d_in[23];
  float* out = (float*)d_out;

  char* ws = (char*)d_ws;
  size_t cur = 0;
  auto alloc = [&](size_t bytes) { size_t r = cur; cur += (bytes + 255) & ~(size_t)255; return r; };
  float* x    = (float*)(ws + alloc((size_t)3552 * 768 * 4));
  float* img  = (float*)(ws + alloc((size_t)3136 * 768 * 4));
  float* qb   = (float*)(ws + alloc((size_t)16 * 768 * 4));
  float* logp = (float*)(ws + alloc(1024));
  int*   tk   = (int*)(ws + alloc(1024));
  float* dg   = (float*)(ws + alloc((size_t)10 * 768 * 4));
  h16_t* h16   = (h16_t*)(ws + alloc((size_t)3552 * 768 * 2));
  size_t qkv_off = alloc((size_t)3552 * 2304 * 2);
  h16_t* qkv16 = (h16_t*)(ws + qkv_off);
  size_t g_off = alloc((size_t)3552 * 3072 * 2);
  h16_t* g16   = (h16_t*)(ws + g_off);
  float* Lbuf  = (float*)(ws + alloc((size_t)10 * 589824 * 4));
  h16_t* wq16  = (h16_t*)(ws + alloc((size_t)12 * 2304 * 768 * 2));
  h16_t* wp16  = (h16_t*)(ws + alloc((size_t)12 * 768 * 768 * 2));
  h16_t* w116  = (h16_t*)(ws + alloc((size_t)12 * 3072 * 768 * 2));
  h16_t* w216  = (h16_t*)(ws + alloc((size_t)12 * 768 * 3072 * 2));
  h16_t* wpt16 = (h16_t*)(ws + alloc((size_t)768 * 768 * 2));
  // phase-disjoint aliases:
  h16_t* col16 = (h16_t*)(ws + g_off);   // im2col (before pass 1)
  float* Ut    = (float*)(ws + qkv_off); // 23.6 MB over qkv16+g16 (MVN phase)

  // -------- weight conversion / transposition (fp32 [K,N] -> fp16 [N,K])
  wcvt_t<<<dim3(72, 24, 12), 256, 0, stream>>>(qkvw, wq16, 768, 2304);
  wcvt_t<<<dim3(24, 24, 12), 256, 0, stream>>>(projw, wp16, 768, 768);
  wcvt_t<<<dim3(96, 24, 12), 256, 0, stream>>>(fc1w, w116, 768, 3072);
  wcvt_t<<<dim3(24, 96, 12), 256, 0, stream>>>(fc2w, w216, 3072, 768);
  cvt_flat<<<2304, 256, 0, stream>>>(patchw, wpt16, 589824);

  // -------- patch embed + x0
  im2col_k<<<9408, 256, 0, stream>>>(inp, col16);
  hgemm_p<<<dim3(25, 6), 512, 0, stream>>>(col16, wpt16, img, patchb,
      3136, 768, 768, 768, 0);
  build_x0_k<<<9456, 256, 0, stream>>>(x, img, cls, pos);

  auto pass = [&](int Ntok) {
    int M = 16 * Ntok;
    int Mt1 = (M + 127) / 128;
    int Mt8 = (M + 255) / 256;
    int Qt = (Ntok + 63) / 64;
    for (int l = 0; l < 12; l++) {
      ln_rows<<<(M + 3) / 4, 256, 0, stream>>>(x, h16, nullptr, ln1g + l * 768, ln1b + l * 768, M, 768, 768);
      hgemm_q<<<dim3(Mt1, 9), 512, 0, stream>>>(h16, wq16 + (size_t)l * 2304 * 768, qkv16,
          qkvb + l * 2304, M, 2304, 768, 2304);
      flash_attn<<<dim3(Qt, 192), 256, 0, stream>>>(qkv16, h16, Ntok);
      hgemm_p<<<dim3(Mt1, 6), 512, 0, stream>>>(h16, wp16 + (size_t)l * 768 * 768, x,
          projb + l * 768, M, 768, 768, 768, 1);
      ln_rows<<<(M + 3) / 4, 256, 0, stream>>>(x, h16, nullptr, ln2g + l * 768, ln2b + l * 768, M, 768, 768);
      hgemm_f<<<dim3(Mt8, 12), 512, 0, stream>>>(h16, w116 + (size_t)l * 3072 * 768, g16,
          fc1b + l * 3072, M, 3072, 768, 3072);
      hgemm_p<<<dim3(Mt1, 6), 512, 0, stream>>>(g16, w216 + (size_t)l * 768 * 3072, x,
          fc2b + l * 768, M, 768, 3072, 768, 1);
    }
  };

  // -------- query pass, q = LN(x)[:,0]
  pass(197);
  ln_rows<<<4, 256, 0, stream>>>(x, nullptr, qb, normg, normb, 16, (long)197 * 768, 768);

  // -------- cov = |var| + I ; right-looking blocked Cholesky (NB=64)
  cov_init_k<<<23040, 256, 0, stream>>>(var, Lbuf);
  for (int m = 0; m < 12; m++) {
    int jb = 64 * m;
    chol_diag<<<10, 64, 0, stream>>>(Lbuf, jb);
    int R = 704 - jb;  // rows below the diag block
    if (R > 0) {
      trsm_off<<<dim3((R + 255) / 256, 10), 256, 0, stream>>>(Lbuf, jb, R);
      syrk_upd<<<dim3(R >> 6, R >> 6, 10), 256, 0, stream>>>(Lbuf, jb);
    }
  }
  ltrans_k<<<dim3(24, 24, 10), 256, 0, stream>>>(Lbuf, Ut, dg);
  trsm2<<<160, 64, 0, stream>>>(Ut, dg, qb, meanp, logp);
  topk_k<<<1, 64, 0, stream>>>(logp, tk);

  // -------- prompted pass + head
  build_x2_k<<<10656, 256, 0, stream>>>(x, img, cls, pos, prompt, tk);
  pass(222);
  final_head<<<16, 256, 0, stream>>>(x, normg, normb, headw, headb, out);
}